// Round 8
// baseline (284.405 us; speedup 1.0000x reference)
//
#include <hip/hip_runtime.h>
#include <cmath>

#define LBINS 401
#define LL 160801
#define MIN_SEP 2
#define PSTRIDE 405      // per-partial floats: 401 bins + HA,HC,SWm,SMm
#define UNR 8

// ws float layout
#define ACC_HANY  401
#define ACC_HCONV 402
#define ACC_SWM   403
#define ACC_SMM   404
#define CNT_OFF   512    // per-batch (nc_b, same_b) pairs, 2*B floats
#define PARTS_OFF 2048

// ---------------------------------------------------------------------------
// per-diagonal inner loop: 1 coalesced global dword + 2 LDS reads + FMA per
// element; no atomics/barriers inside -> loads stay hoisted (UNR in flight).
// ---------------------------------------------------------------------------
__device__ __forceinline__ void run_diag(
    const float* __restrict__ cmb, const float4* colm, const float4* rowm,
    int k, int i0, int ie,
    float& HA, float& HC, float& SMk, float& SMw, float& SWk, float& SWw) {
    int i = i0;
    for (; i + UNR <= ie; i += UNR) {
        float  cv[UNR], sw[UNR];
        float4 cj4[UNR], rm4[UNR];
        #pragma unroll
        for (int q = 0; q < UNR; ++q) {
            int ii = i + q;
            int j  = ii + k;
            int wrapped = (j >= LBINS);
            int jc = wrapped ? j - LBINS : j;
            cv[q]  = cmb[(size_t)ii * LBINS + jc];
            cj4[q] = colm[jc];
            rm4[q] = rowm[ii];
            sw[q]  = wrapped ? 1.f : 0.f;
        }
        #pragma unroll
        for (int q = 0; q < UNR; ++q) {
            float c  = cv[q];
            float rc = fmaxf(c, 0.f);
            HA = fmaf(rm4[q].x * cj4[q].x, rc, HA);
            HC = fmaf(rm4[q].y * cj4[q].y, rc, HC);
            float same = fmaf(rm4[q].z, cj4[q].z, rm4[q].w);
            float sc = same * c;
            float s = sw[q];
            SWw = fmaf(s, sc, SWw);
            SWk = fmaf(1.f - s, sc, SWk);
            SMw = fmaf(s, c, SMw);
            SMk = fmaf(1.f - s, c, SMk);
        }
    }
    for (; i < ie; ++i) {
        int j  = i + k;
        int wrapped = (j >= LBINS);
        int jc = wrapped ? j - LBINS : j;
        float c = cmb[(size_t)i * LBINS + jc];
        float4 cjv = colm[jc];
        float4 rm  = rowm[i];
        float s = wrapped ? 1.f : 0.f;
        float rc = fmaxf(c, 0.f);
        HA = fmaf(rm.x * cjv.x, rc, HA);
        HC = fmaf(rm.y * cjv.y, rc, HC);
        float same = fmaf(rm.z, cjv.z, rm.w);
        float sc = same * c;
        SWw = fmaf(s, sc, SWw);
        SWk = fmaf(1.f - s, sc, SWk);
        SMw = fmaf(s, c, SMw);
        SMk = fmaf(1.f - s, c, SMk);
    }
}

// ---------------------------------------------------------------------------
// diag (skewed torus, 2-pass k coverage): block = (batch b, i-quarter).
// Pass A: lane u owns diagonal k=u (all 256). Pass B: k=256+u for u<145
// (wave 3 skips via execz). d = k or 401-k: register accumulators.
// Quarter-0 blocks also emit the per-batch closed-form counts from LDS.
// ---------------------------------------------------------------------------
__global__ __launch_bounds__(256)
void diag_kernel(const float* __restrict__ cm,
                 const float* __restrict__ logits,
                 const int* __restrict__ ctcf,
                 float* __restrict__ cnt,
                 float* __restrict__ parts) {
    int b = blockIdx.x;
    int qr = blockIdx.y;
    int u = threadIdx.x;

    __shared__ float4 colm[LBINS];   // (any_j, rev_j, c_j, 0)
    __shared__ float4 rowm[LBINS];   // (any_i, fwd_i, 2c_i-1, 1-c_i)
    __shared__ float  lb[LBINS];
    __shared__ float  sred[4][4];
    __shared__ float  cred[4][5];

    const int*   ct = ctcf   + (size_t)b * LBINS;
    const float* lg = logits + (size_t)b * LBINS * 2;
    for (int t = u; t < LBINS; t += 256) {
        int o = ct[t];
        float any = (o != 0) ? 1.f : 0.f;
        float rev = (o == -1) ? 1.f : 0.f;
        float fwd = (o == 1) ? 1.f : 0.f;
        float cj  = (lg[2 * t + 1] > lg[2 * t]) ? 1.f : 0.f;
        colm[t] = make_float4(any, rev, cj, 0.f);
        rowm[t] = make_float4(any, fwd, 2.f * cj - 1.f, 1.f - cj);
        lb[t] = 0.f;
    }
    __syncthreads();

    // per-batch closed-form counts (quarter-0 blocks only; fp32 exact)
    if (qr == 0) {
        float n1 = 0.f, nf = 0.f, nr = 0.f, na = 0.f, adj = 0.f;
        for (int t = u; t < LBINS; t += 256) {
            float4 cv = colm[t];
            n1 += cv.z; na += cv.x; nr += cv.y;
            nf += rowm[t].y;
            if (t >= 1) adj += (colm[t - 1].z == cv.z) ? 1.f : 0.f;
        }
        #pragma unroll
        for (int off = 32; off > 0; off >>= 1) {
            n1 += __shfl_down(n1, off, 64);
            nf += __shfl_down(nf, off, 64);
            nr += __shfl_down(nr, off, 64);
            na += __shfl_down(na, off, 64);
            adj += __shfl_down(adj, off, 64);
        }
        int w = u >> 6;
        if ((u & 63) == 0) {
            cred[w][0] = n1; cred[w][1] = nf; cred[w][2] = nr;
            cred[w][3] = na; cred[w][4] = adj;
        }
        __syncthreads();
        if (u == 0) {
            float N1 = 0.f, NF = 0.f, NR = 0.f, NA = 0.f, AD = 0.f;
            #pragma unroll
            for (int q = 0; q < 4; ++q) {
                N1 += cred[q][0]; NF += cred[q][1]; NR += cred[q][2];
                NA += cred[q][3]; AD += cred[q][4];
            }
            float N0 = (float)LBINS - N1;
            cnt[2 * b]     = NA * NA - NF * NR;
            cnt[2 * b + 1] = N0 * N0 + N1 * N1 - (float)LBINS - 2.f * AD;
        }
    }

    int i0 = (qr * LBINS) >> 2;
    int ie = ((qr + 1) * LBINS) >> 2;
    const float* cmb = cm + (size_t)b * LL;

    float HA = 0.f, HC = 0.f, SWm = 0.f, SMm = 0.f;

    // ---- pass A: k = u (all lanes) ----
    {
        int k = u;
        float SMk = 0.f, SMw = 0.f, SWk = 0.f, SWw = 0.f;
        run_diag(cmb, colm, rowm, k, i0, ie, HA, HC, SMk, SMw, SWk, SWw);
        int dw = LBINS - k;
        atomicAdd(&lb[k], SMk);
        if (k > 0) atomicAdd(&lb[dw], SMw);
        float mk = (k >= MIN_SEP) ? 1.f : 0.f;
        float mw = (dw >= MIN_SEP) ? 1.f : 0.f;
        SWm += SWk * mk + SWw * mw;
        SMm += SMk * mk + SMw * mw;
    }
    // ---- pass B: k = 256 + u (u < 145; wave 3 skips via execz) ----
    if (u < LBINS - 256) {
        int k = 256 + u;
        float SMk = 0.f, SMw = 0.f, SWk = 0.f, SWw = 0.f;
        run_diag(cmb, colm, rowm, k, i0, ie, HA, HC, SMk, SMw, SWk, SWw);
        int dw = LBINS - k;
        atomicAdd(&lb[k], SMk);
        atomicAdd(&lb[dw], SMw);
        SWm += SWk + SWw;      // k >= 2 and dw >= 2 always here
        SMm += SMk + SMw;
    }

    #pragma unroll
    for (int off = 32; off > 0; off >>= 1) {
        HA  += __shfl_down(HA,  off, 64);
        HC  += __shfl_down(HC,  off, 64);
        SWm += __shfl_down(SWm, off, 64);
        SMm += __shfl_down(SMm, off, 64);
    }
    int w = u >> 6;
    if ((u & 63) == 0) {
        sred[w][0] = HA; sred[w][1] = HC; sred[w][2] = SWm; sred[w][3] = SMm;
    }
    __syncthreads();

    float* pout = parts + (size_t)(qr * gridDim.x + b) * PSTRIDE;
    for (int t = u; t < LBINS; t += 256) pout[t] = lb[t];
    if (u == 0) {
        float a = 0.f, c2 = 0.f, s = 0.f, m = 0.f;
        #pragma unroll
        for (int q = 0; q < 4; ++q) {
            a += sred[q][0]; c2 += sred[q][1]; s += sred[q][2]; m += sred[q][3];
        }
        pout[401] = a; pout[402] = c2; pout[403] = s; pout[404] = m;
    }
}

// ---------------------------------------------------------------------------
// reduce: block s sums column s over all partials -> accum[s] (plain store).
// ---------------------------------------------------------------------------
__global__ __launch_bounds__(256)
void reduce_kernel(const float* __restrict__ parts,
                   float* __restrict__ accum, int npart) {
    int s = blockIdx.x;
    int u = threadIdx.x;
    float acc = 0.f;
    for (int p = u; p < npart; p += 256) acc += parts[(size_t)p * PSTRIDE + s];
    #pragma unroll
    for (int off = 32; off > 0; off >>= 1) acc += __shfl_down(acc, off, 64);
    __shared__ float r[4];
    if ((u & 63) == 0) r[u >> 6] = acc;
    __syncthreads();
    if (u == 0) accum[s] = r[0] + r[1] + r[2] + r[3];
}

// ---------------------------------------------------------------------------
__device__ double block_reduce_d(double v, double* buf) {
    int tid = threadIdx.x;
    buf[tid] = v;
    __syncthreads();
    for (int off = blockDim.x >> 1; off > 0; off >>= 1) {
        if (tid < off) buf[tid] += buf[tid + off];
        __syncthreads();
    }
    double r = buf[0];
    __syncthreads();
    return r;
}

__global__ __launch_bounds__(512)
void final_kernel(const float* __restrict__ accum,
                  const float* __restrict__ cnt,
                  float* __restrict__ out, int B) {
    __shared__ double dred[512];
    int tid = threadIdx.x;

    double ncl = 0.0, samel = 0.0;
    for (int p = tid; p < B; p += 512) {
        ncl   += (double)cnt[2 * p];
        samel += (double)cnt[2 * p + 1];
    }
    double nc_sum   = block_reduce_d(ncl, dred);
    double same_cnt = block_reduce_d(samel, dred);
    double total_maskf = (double)B * ((double)LL - 3.0 * LBINS + 2.0);
    double diff_cnt = total_maskf - same_cnt;

    float wgt = 0.f, x = 0.f, y = 0.f;
    if (tid < LBINS) {
        float cntB = ((tid == 0) ? (float)LBINS : 2.0f * (float)(LBINS - tid)) * (float)B;
        float mc = accum[tid] / cntB;
        int valid = (tid >= MIN_SEP) && __builtin_isfinite(mc) && (mc > 0.0f);
        wgt = valid ? 1.f : 0.f;
        x = logf(fmaxf((float)tid, 1.0f));
        y = logf((valid ? mc : 1.0f) + 1e-6f);
    }
    double n  = block_reduce_d((double)wgt, dred);
    double Sx = block_reduce_d((double)wgt * x, dred);
    double Sy = block_reduce_d((double)wgt * y, dred);
    double n_safe = fmax(n, 1.0);
    double xm = Sx / n_safe, ym = Sy / n_safe;
    double num = block_reduce_d((double)wgt * ((double)x - xm) * ((double)y - ym), dred);
    double den = block_reduce_d((double)wgt * ((double)x - xm) * ((double)x - xm), dred);

    if (tid == 0) {
        double slope = num / (den + 1e-8);
        float dist_loss = (n >= 5.0) ? (float)((slope + 0.85) * (slope + 0.85)) : 0.0f;

        float ncf = (float)nc_sum;
        float hinge = (accum[ACC_HANY] - accum[ACC_HCONV]) / (ncf + 1e-6f);
        float ctcf_loss = (ncf < 1.0f) ? 0.0f : hinge;

        float SW_m = accum[ACC_SWM];
        float SM_m = accum[ACC_SMM];
        float within  = SW_m / (float)fmax(same_cnt, 1.0);
        float between = (SM_m - SW_m) / (float)fmax(diff_cnt, 1.0);
        float ratio = within / (fabsf(between) + 1e-6f);
        float comp_loss = fmaxf(1.5f - ratio, 0.0f);

        float total = 1.0f * dist_loss + 0.5f * ctcf_loss + 0.5f * comp_loss;
        out[0] = dist_loss;
        out[1] = ctcf_loss;
        out[2] = comp_loss;
        out[3] = total;
    }
}

// ---------------------------------------------------------------------------
extern "C" void kernel_launch(void* const* d_in, const int* in_sizes, int n_in,
                              void* d_out, int out_size, void* d_ws, size_t ws_size,
                              hipStream_t stream) {
    const float* cm     = (const float*)d_in[0];   // (B, L, L) fp32
    const float* logits = (const float*)d_in[1];   // (B, L, 2) fp32
    const int*   ctcf   = (const int*)d_in[2];     // (B, L) int32
    float* out = (float*)d_out;

    int total = in_sizes[0];
    int B = total / LL;

    float* wsf   = (float*)d_ws;
    float* accum = wsf;
    float* cnt   = wsf + CNT_OFF;
    float* parts = wsf + PARTS_OFF;

    diag_kernel<<<dim3(B, 4), 256, 0, stream>>>(cm, logits, ctcf, cnt, parts);
    reduce_kernel<<<PSTRIDE, 256, 0, stream>>>(parts, accum, 4 * B);
    final_kernel<<<1, 512, 0, stream>>>(accum, cnt, out, B);
}